// Round 1
// baseline (2433.744 us; speedup 1.0000x reference)
//
#include <hip/hip_runtime.h>

#define NF 32
#define EPSF 1e-9f

// ---------------- scatter (grid_create accumulation) ----------------
// one thread per (creator point n, feature lane f). 2^D corner atomics each.

__global__ __launch_bounds__(256) void scatter3d_kernel(
    const float* __restrict__ xyz, const float* __restrict__ feat,
    float* __restrict__ wf, float* __restrict__ ws, int N, int R) {
  int t = blockIdx.x * blockDim.x + threadIdx.x;
  int n = t >> 5;
  int f = t & 31;
  if (n >= N) return;
  float s = (float)(R - 1);
  float x = xyz[n * 3 + 0] * s;
  float y = xyz[n * 3 + 1] * s;
  float z = xyz[n * 3 + 2] * s;
  float fx = floorf(x), fy = floorf(y), fz = floorf(z);
  float rx = x - fx, ry = y - fy, rz = z - fz;
  int ix = (int)fx, iy = (int)fy, iz = (int)fz;
  float v = feat[(size_t)n * NF + f];
#pragma unroll
  for (int c = 0; c < 8; ++c) {
    int bx = (c >> 2) & 1, by = (c >> 1) & 1, bz = c & 1;
    int cx = min(max(ix + bx, 0), R - 1);
    int cy = min(max(iy + by, 0), R - 1);
    int cz = min(max(iz + bz, 0), R - 1);
    float w = (bx ? rx : 1.f - rx) * (by ? ry : 1.f - ry) * (bz ? rz : 1.f - rz);
    int idx = (cx * R + cy) * R + cz;
    atomicAdd(&wf[(size_t)idx * NF + f], w * v);
    if (f == 0) atomicAdd(&ws[idx], w);
  }
}

__global__ __launch_bounds__(256) void scatter2d_kernel(
    const float* __restrict__ xyz, const float* __restrict__ feat,
    float* __restrict__ wf, float* __restrict__ ws, int N, int R, int d0, int d1) {
  int t = blockIdx.x * blockDim.x + threadIdx.x;
  int n = t >> 5;
  int f = t & 31;
  if (n >= N) return;
  float s = (float)(R - 1);
  float x = xyz[n * 3 + d0] * s;
  float y = xyz[n * 3 + d1] * s;
  float fx = floorf(x), fy = floorf(y);
  float rx = x - fx, ry = y - fy;
  int ix = (int)fx, iy = (int)fy;
  float v = feat[(size_t)n * NF + f];
#pragma unroll
  for (int c = 0; c < 4; ++c) {
    int bx = (c >> 1) & 1, by = c & 1;
    int cx = min(max(ix + bx, 0), R - 1);
    int cy = min(max(iy + by, 0), R - 1);
    float w = (bx ? rx : 1.f - rx) * (by ? ry : 1.f - ry);
    int idx = cx * R + cy;
    atomicAdd(&wf[(size_t)idx * NF + f], w * v);
    if (f == 0) atomicAdd(&ws[idx], w);
  }
}

// ---------------- encode (normalize-on-the-fly gather) ----------------
// one thread per (interp point m, feature lane f).

__global__ __launch_bounds__(256) void encode3d_kernel(
    const float* __restrict__ xyz, const float* __restrict__ wf,
    const float* __restrict__ ws, float* __restrict__ out, int M, int R, int slot) {
  int t = blockIdx.x * blockDim.x + threadIdx.x;
  int m = t >> 5;
  int f = t & 31;
  if (m >= M) return;
  float s = (float)(R - 1);
  float x = xyz[m * 3 + 0] * s;
  float y = xyz[m * 3 + 1] * s;
  float z = xyz[m * 3 + 2] * s;
  float fx = floorf(x), fy = floorf(y), fz = floorf(z);
  float rx = x - fx, ry = y - fy, rz = z - fz;
  int ix = (int)fx, iy = (int)fy, iz = (int)fz;
  float acc = 0.f;
#pragma unroll
  for (int c = 0; c < 8; ++c) {
    int bx = (c >> 2) & 1, by = (c >> 1) & 1, bz = c & 1;
    int cx = min(max(ix + bx, 0), R - 1);
    int cy = min(max(iy + by, 0), R - 1);
    int cz = min(max(iz + bz, 0), R - 1);
    float w = (bx ? rx : 1.f - rx) * (by ? ry : 1.f - ry) * (bz ? rz : 1.f - rz);
    int idx = (cx * R + cy) * R + cz;
    float d = fmaxf(ws[idx], EPSF);
    acc += w * wf[(size_t)idx * NF + f] / d;
  }
  out[(size_t)m * 384 + slot * 32 + f] = acc;
}

__global__ __launch_bounds__(256) void encode2d_kernel(
    const float* __restrict__ xyz, const float* __restrict__ wf,
    const float* __restrict__ ws, float* __restrict__ out, int M, int R, int slot,
    int d0, int d1) {
  int t = blockIdx.x * blockDim.x + threadIdx.x;
  int m = t >> 5;
  int f = t & 31;
  if (m >= M) return;
  float s = (float)(R - 1);
  float x = xyz[m * 3 + d0] * s;
  float y = xyz[m * 3 + d1] * s;
  float fx = floorf(x), fy = floorf(y);
  float rx = x - fx, ry = y - fy;
  int ix = (int)fx, iy = (int)fy;
  float acc = 0.f;
#pragma unroll
  for (int c = 0; c < 4; ++c) {
    int bx = (c >> 1) & 1, by = c & 1;
    int cx = min(max(ix + bx, 0), R - 1);
    int cy = min(max(iy + by, 0), R - 1);
    float w = (bx ? rx : 1.f - rx) * (by ? ry : 1.f - ry);
    int idx = cx * R + cy;
    float d = fmaxf(ws[idx], EPSF);
    acc += w * wf[(size_t)idx * NF + f] / d;
  }
  out[(size_t)m * 384 + slot * 32 + f] = acc;
}

extern "C" void kernel_launch(void* const* d_in, const int* in_sizes, int n_in,
                              void* d_out, int out_size, void* d_ws, size_t ws_size,
                              hipStream_t stream) {
  const float* xyz_c = (const float*)d_in[0];
  const float* xyz_i = (const float*)d_in[1];
  const float* feat = (const float*)d_in[2];
  float* out = (float*)d_out;
  int N = in_sizes[0] / 3;
  int M = in_sizes[1] / 3;

  // workspace: reuse one max-size grid region per pass.
  const size_t maxcells = 64ull * 64 * 64;  // 262144, largest grid
  float* wf = (float*)d_ws;
  float* ws = wf + maxcells * NF;  // 33.5 MB in, 1 MB for weight sums

  const int bs = 256;
  int sblocks = (N * 32 + bs - 1) / bs;
  int eblocks = (M * 32 + bs - 1) / bs;

  int slot = 0;
  const int R3[3] = {16, 32, 64};
  for (int i = 0; i < 3; ++i) {
    int R = R3[i];
    size_t cells = (size_t)R * R * R;
    hipMemsetAsync(wf, 0, cells * NF * sizeof(float), stream);
    hipMemsetAsync(ws, 0, cells * sizeof(float), stream);
    scatter3d_kernel<<<sblocks, bs, 0, stream>>>(xyz_c, feat, wf, ws, N, R);
    encode3d_kernel<<<eblocks, bs, 0, stream>>>(xyz_i, wf, ws, out, M, R, slot);
    ++slot;
  }

  const int dp[3][2] = {{0, 1}, {0, 2}, {1, 2}};
  const int R2[3] = {64, 128, 256};
  for (int p = 0; p < 3; ++p) {
    for (int i = 0; i < 3; ++i) {
      int R = R2[i];
      size_t cells = (size_t)R * R;
      hipMemsetAsync(wf, 0, cells * NF * sizeof(float), stream);
      hipMemsetAsync(ws, 0, cells * sizeof(float), stream);
      scatter2d_kernel<<<sblocks, bs, 0, stream>>>(xyz_c, feat, wf, ws, N, R, dp[p][0], dp[p][1]);
      encode2d_kernel<<<eblocks, bs, 0, stream>>>(xyz_i, wf, ws, out, M, R, slot, dp[p][0], dp[p][1]);
      ++slot;
    }
  }
}

// Round 2
// 1587.326 us; speedup vs baseline: 1.5332x; 1.5332x over previous
//
#include <hip/hip_runtime.h>

#define NF 32
#define EPSF 1e-9f

__device__ __forceinline__ int cell_coord(float xv, int R, float& fr) {
  float x = xv * (float)(R - 1);
  int i0 = (int)floorf(x);
  i0 = min(max(i0, 0), R - 2);
  fr = x - (float)i0;
  return i0;
}

// ---------- histogram: key per point + bin counts ----------
template <int D>
__global__ __launch_bounds__(256) void hist_kernel(
    const float* __restrict__ xyz, int* __restrict__ keys, int* __restrict__ cnt,
    int N, int R, int d0, int d1) {
  int p = blockIdx.x * blockDim.x + threadIdx.x;
  if (p >= N) return;
  int key = 0;
  float fr;
#pragma unroll
  for (int d = 0; d < D; ++d) {
    int dim = (D == 3) ? d : (d == 0 ? d0 : d1);
    int i0 = cell_coord(xyz[p * 3 + dim], R, fr);
    key = key * R + i0;
  }
  keys[p] = key;
  atomicAdd(&cnt[key], 1);
}

// ---------- hierarchical exclusive scan over cnt[K] -> cur[K] ----------
__global__ __launch_bounds__(256) void scan_blocksum(
    const int* __restrict__ cnt, int* __restrict__ bsum, int K) {
  __shared__ int red[256];
  int base = blockIdx.x * 2048 + threadIdx.x * 8;
  int s = 0;
#pragma unroll
  for (int j = 0; j < 8; ++j) {
    int k = base + j;
    if (k < K) s += cnt[k];
  }
  red[threadIdx.x] = s;
  __syncthreads();
  for (int off = 128; off > 0; off >>= 1) {
    if (threadIdx.x < off) red[threadIdx.x] += red[threadIdx.x + off];
    __syncthreads();
  }
  if (threadIdx.x == 0) bsum[blockIdx.x] = red[0];
}

__global__ __launch_bounds__(256) void scan_write(
    const int* __restrict__ cnt, const int* __restrict__ bsum,
    int* __restrict__ cur, int K) {
  __shared__ int lds[256];
  __shared__ int boff;
  int b = blockIdx.x, t = threadIdx.x;
  if (t == 0) {
    int s = 0;
    for (int j = 0; j < b; ++j) s += bsum[j];
    boff = s;
  }
  int base = b * 2048 + t * 8;
  int v[8];
  int s = 0;
#pragma unroll
  for (int j = 0; j < 8; ++j) {
    int k = base + j;
    v[j] = (k < K) ? cnt[k] : 0;
    s += v[j];
  }
  lds[t] = s;
  __syncthreads();
  for (int off = 1; off < 256; off <<= 1) {
    int add = (t >= off) ? lds[t - off] : 0;
    __syncthreads();
    lds[t] += add;
    __syncthreads();
  }
  int run = boff + lds[t] - s;  // exclusive prefix for this thread's 8 elems
#pragma unroll
  for (int j = 0; j < 8; ++j) {
    int k = base + j;
    if (k < K) {
      cur[k] = run;
      run += v[j];
    }
  }
}

// ---------- placement: sidx sorted by cell (cur becomes bin END) ----------
__global__ __launch_bounds__(256) void place_kernel(
    const int* __restrict__ keys, int* __restrict__ cur, int* __restrict__ sidx, int N) {
  int p = blockIdx.x * blockDim.x + threadIdx.x;
  if (p >= N) return;
  int pos = atomicAdd(&cur[keys[p]], 1);
  sidx[pos] = p;
}

// ---------- gather-create: one wave per cell, writes NORMALIZED grid ----------
template <int D>
__global__ __launch_bounds__(256) void create_kernel(
    const float* __restrict__ xyz, const float* __restrict__ feat,
    const int* __restrict__ sidx, const int* __restrict__ cur_end,
    const int* __restrict__ cnt, float* __restrict__ grid,
    int R, int d0, int d1) {
  int lane = threadIdx.x & 63;
  int wave = threadIdx.x >> 6;
  int f = lane & 31, half = lane >> 5;
  int K = (D == 3) ? R * R * R : R * R;
  int cell = blockIdx.x * 4 + wave;
  if (cell >= K) return;
  int c[3];
  if (D == 3) {
    c[0] = cell / (R * R);
    c[1] = (cell / R) % R;
    c[2] = cell % R;
  } else {
    c[0] = cell / R;
    c[1] = cell % R;
  }
  float acc = 0.f, wsum = 0.f;
#pragma unroll
  for (int cb = 0; cb < (1 << D); ++cb) {
    int b[3];
    bool ok = true;
#pragma unroll
    for (int d = 0; d < D; ++d) {
      int o = (cb >> d) & 1;
      b[d] = c[d] - o;
      if (b[d] < 0 || b[d] > R - 2) ok = false;
    }
    if (!ok) continue;
    int kb = (D == 3) ? (b[0] * R + b[1]) * R + b[2] : b[0] * R + b[1];
    int e = cur_end[kb];
    int n = cnt[kb];
    int beg = e - n;
    for (int i = half; i < n; i += 2) {
      int q = sidx[beg + i];
      float w = 1.f;
#pragma unroll
      for (int d = 0; d < D; ++d) {
        int dim = (D == 3) ? d : (d == 0 ? d0 : d1);
        float fr;
        cell_coord(xyz[q * 3 + dim], R, fr);
        w *= (b[d] == c[d]) ? (1.f - fr) : fr;  // offset 0 -> (1-fr), 1 -> fr
      }
      acc += w * feat[(size_t)q * NF + f];
      wsum += w;
    }
  }
  acc += __shfl_xor(acc, 32);
  wsum += __shfl_xor(wsum, 32);
  if (half == 0) grid[(size_t)cell * NF + f] = acc / fmaxf(wsum, EPSF);
}

// ---------- encode from normalized grid ----------
template <int D>
__global__ __launch_bounds__(256) void encode_kernel(
    const float* __restrict__ xyz, const float* __restrict__ grid,
    float* __restrict__ out, int M, int R, int slot, int d0, int d1) {
  int t = blockIdx.x * blockDim.x + threadIdx.x;
  int m = t >> 5, f = t & 31;
  if (m >= M) return;
  float fr[3];
  int ix[3];
#pragma unroll
  for (int d = 0; d < D; ++d) {
    int dim = (D == 3) ? d : (d == 0 ? d0 : d1);
    ix[d] = cell_coord(xyz[m * 3 + dim], R, fr[d]);
  }
  float acc = 0.f;
#pragma unroll
  for (int cb = 0; cb < (1 << D); ++cb) {
    float w = 1.f;
    int idx = 0;
#pragma unroll
    for (int d = 0; d < D; ++d) {
      int o = (cb >> d) & 1;
      w *= o ? fr[d] : (1.f - fr[d]);
      idx = idx * R + (ix[d] + o);
    }
    acc += w * grid[(size_t)idx * NF + f];
  }
  out[(size_t)m * 384 + slot * 32 + f] = acc;
}

extern "C" void kernel_launch(void* const* d_in, const int* in_sizes, int n_in,
                              void* d_out, int out_size, void* d_ws, size_t ws_size,
                              hipStream_t stream) {
  const float* xyz_c = (const float*)d_in[0];
  const float* xyz_i = (const float*)d_in[1];
  const float* feat = (const float*)d_in[2];
  float* out = (float*)d_out;
  int N = in_sizes[0] / 3;
  int M = in_sizes[1] / 3;

  // workspace layout (reused per grid); peak ~37.8 MB
  int* cnt = (int*)d_ws;          // 262144
  int* cur = cnt + 262144;        // 262144
  int* keys = cur + 262144;       // 200064
  int* sidx = keys + 200064;      // 200064
  int* bsum = sidx + 200064;      // 256
  float* grid = (float*)d_ws + (1 << 20);  // at 4 MB; up to 262144*32 floats

  auto run = [&](int D, int R, int slot, int d0, int d1) {
    int K = (D == 3) ? R * R * R : R * R;
    int nb = (K + 2047) / 2048;
    hipMemsetAsync(cnt, 0, (size_t)K * sizeof(int), stream);
    if (D == 3)
      hist_kernel<3><<<(N + 255) / 256, 256, 0, stream>>>(xyz_c, keys, cnt, N, R, 0, 1);
    else
      hist_kernel<2><<<(N + 255) / 256, 256, 0, stream>>>(xyz_c, keys, cnt, N, R, d0, d1);
    scan_blocksum<<<nb, 256, 0, stream>>>(cnt, bsum, K);
    scan_write<<<nb, 256, 0, stream>>>(cnt, bsum, cur, K);
    place_kernel<<<(N + 255) / 256, 256, 0, stream>>>(keys, cur, sidx, N);
    int cblocks = (K + 3) / 4;
    int eblocks = (M * 32 + 255) / 256;
    if (D == 3) {
      create_kernel<3><<<cblocks, 256, 0, stream>>>(xyz_c, feat, sidx, cur, cnt, grid, R, 0, 1);
      encode_kernel<3><<<eblocks, 256, 0, stream>>>(xyz_i, grid, out, M, R, slot, 0, 1);
    } else {
      create_kernel<2><<<cblocks, 256, 0, stream>>>(xyz_c, feat, sidx, cur, cnt, grid, R, d0, d1);
      encode_kernel<2><<<eblocks, 256, 0, stream>>>(xyz_i, grid, out, M, R, slot, d0, d1);
    }
  };

  int slot = 0;
  const int R3[3] = {16, 32, 64};
  for (int i = 0; i < 3; ++i) run(3, R3[i], slot++, 0, 1);

  const int dp[3][2] = {{0, 1}, {0, 2}, {1, 2}};
  const int R2[3] = {64, 128, 256};
  for (int p = 0; p < 3; ++p)
    for (int i = 0; i < 3; ++i) run(2, R2[i], slot++, dp[p][0], dp[p][1]);
}